// Round 2
// baseline (1066.008 us; speedup 1.0000x reference)
//
#include <hip/hip_runtime.h>

// Problem constants (match reference)
constexpr int   N_NODES = 80000;
constexpr int   N_EDGE  = 2560000;
constexpr int   IN_DIM  = 128;
constexpr int   H1      = 32;
constexpr int   H2      = 64;
constexpr int   NPB     = 10000;   // nodes per batch
constexpr int   NB      = 8;       // batches

// ---------------- init: deg = 1 (self loop), partial = 0 ----------------
__global__ void k_init(unsigned* __restrict__ deg, double* __restrict__ partial) {
    int i = blockIdx.x * blockDim.x + threadIdx.x;
    if (i < N_NODES) deg[i] = 1u;
    if (i < NB) partial[i] = 0.0;
}

// ---------------- degree count: deg[dst]++ ----------------
__global__ void k_deg(const int* __restrict__ ei, unsigned* __restrict__ deg) {
    int e = blockIdx.x * blockDim.x + threadIdx.x;
    if (e >= N_EDGE) return;
    atomicAdd(&deg[ei[N_EDGE + e]], 1u);
}

// ---------------- dinv = rsqrt(deg) ----------------
__global__ void k_dinv(const unsigned* __restrict__ deg, float* __restrict__ dinv) {
    int i = blockIdx.x * blockDim.x + threadIdx.x;
    if (i < N_NODES) dinv[i] = rsqrtf((float)deg[i]);
}

// ---------------- per-edge norm = dinv[src]*dinv[dst] ----------------
__global__ void k_norm(const int* __restrict__ ei, const float* __restrict__ dinv,
                       float* __restrict__ norm) {
    int e = blockIdx.x * blockDim.x + threadIdx.x;
    if (e >= N_EDGE) return;
    norm[e] = dinv[ei[e]] * dinv[ei[N_EDGE + e]];
}

// ---------------- GEMM1: xW1 = x @ W1 ; agg1 = xW1 * dinv^2 (self loop) ----
__global__ __launch_bounds__(256) void k_gemm1(
        const float* __restrict__ x, const float* __restrict__ W1,
        const float* __restrict__ dinv,
        float* __restrict__ xW1, float* __restrict__ agg1) {
    __shared__ float W1s[IN_DIM * H1];   // 16 KB
    int tid = threadIdx.x;
    for (int i = tid; i < IN_DIM * H1; i += 256) W1s[i] = W1[i];
    __syncthreads();
    int r = tid >> 5, c = tid & 31;
    int row = blockIdx.x * 8 + r;
    if (row >= N_NODES) return;
    const float4* x4 = reinterpret_cast<const float4*>(x + (long long)row * IN_DIM);
    float acc = 0.f;
#pragma unroll
    for (int j = 0; j < IN_DIM / 4; ++j) {
        float4 xv = x4[j];
        acc += xv.x * W1s[(4 * j + 0) * H1 + c];
        acc += xv.y * W1s[(4 * j + 1) * H1 + c];
        acc += xv.z * W1s[(4 * j + 2) * H1 + c];
        acc += xv.w * W1s[(4 * j + 3) * H1 + c];
    }
    xW1[row * H1 + c] = acc;
    float dv = dinv[row];
    agg1[row * H1 + c] = acc * dv * dv;
}

// ---------------- scatter layer 1: agg1[dst] += xW1[src] * norm ----------
__global__ __launch_bounds__(256) void k_scatter1(
        const int* __restrict__ ei, const float* __restrict__ norm,
        const float* __restrict__ xW1, float* __restrict__ agg1) {
    int idx = blockIdx.x * blockDim.x + threadIdx.x;   // < E*32 = 81.92M
    int e = idx >> 5;
    int f = idx & 31;
    if (e >= N_EDGE) return;
    int s = ei[e];
    int d = ei[N_EDGE + e];
    float v = xW1[s * H1 + f] * norm[e];
    unsafeAtomicAdd(&agg1[d * H1 + f], v);
}

// ---------------- GEMM2: h2 = relu(agg1+b1) @ W2 ; agg2 = h2 * dinv^2 ----
__global__ __launch_bounds__(256) void k_gemm2(
        const float* __restrict__ agg1, const float* __restrict__ b1,
        const float* __restrict__ W2, const float* __restrict__ dinv,
        float* __restrict__ h2, float* __restrict__ agg2) {
    __shared__ float W2s[H1 * H2];   // 8 KB
    __shared__ float b1s[H1];
    int tid = threadIdx.x;
    for (int i = tid; i < H1 * H2; i += 256) W2s[i] = W2[i];
    if (tid < H1) b1s[tid] = b1[tid];
    __syncthreads();
    int r = tid >> 6, c = tid & 63;
    int row = blockIdx.x * 4 + r;
    if (row >= N_NODES) return;
    float acc = 0.f;
#pragma unroll
    for (int k = 0; k < H1; ++k) {
        float hk = fmaxf(agg1[row * H1 + k] + b1s[k], 0.f);
        acc += hk * W2s[k * H2 + c];
    }
    h2[row * H2 + c] = acc;
    float dv = dinv[row];
    agg2[row * H2 + c] = acc * dv * dv;
}

// ---------------- scatter layer 2: agg2[dst] += h2[src] * norm ----------
__global__ __launch_bounds__(256) void k_scatter2(
        const int* __restrict__ ei, const float* __restrict__ norm,
        const float* __restrict__ h2, float* __restrict__ agg2) {
    int idx = blockIdx.x * blockDim.x + threadIdx.x;   // < E*64 = 163.84M
    int e = idx >> 6;
    int f = idx & 63;
    if (e >= N_EDGE) return;
    int s = ei[e];
    int d = ei[N_EDGE + e];
    float v = h2[s * H2 + f] * norm[e];
    unsafeAtomicAdd(&agg2[d * H2 + f], v);
}

// ---------------- readout: partial[b] += sum relu(agg2+b2)*Wout ----------
__global__ __launch_bounds__(256) void k_final(
        const float* __restrict__ agg2, const float* __restrict__ b2,
        const float* __restrict__ Wout, double* __restrict__ partial) {
    int b = blockIdx.y;
    __shared__ float b2s[H2];
    int tid = threadIdx.x;
    if (tid < H2) b2s[tid] = b2[tid];
    __syncthreads();
    const int per_batch = NPB * H2;   // 640000
    double acc = 0.0;
    for (int i = blockIdx.x * blockDim.x + tid; i < per_batch;
         i += gridDim.x * blockDim.x) {
        float h = fmaxf(agg2[b * per_batch + i] + b2s[i & 63], 0.f);
        acc += (double)(h * Wout[i]);
    }
    for (int off = 32; off; off >>= 1) acc += __shfl_down(acc, off, 64);
    __shared__ double sred[4];
    if ((tid & 63) == 0) sred[tid >> 6] = acc;
    __syncthreads();
    if (tid == 0) {
        double s = sred[0] + sred[1] + sred[2] + sred[3];
        unsafeAtomicAdd(&partial[b], s);
    }
}

// ---------------- write out ----------------
__global__ void k_out(const double* __restrict__ partial,
                      const float* __restrict__ bout, float* __restrict__ out) {
    int b = threadIdx.x;
    if (b < NB) out[b] = (float)(partial[b] + (double)bout[0]);
}

extern "C" void kernel_launch(void* const* d_in, const int* in_sizes, int n_in,
                              void* d_out, int out_size, void* d_ws, size_t ws_size,
                              hipStream_t stream) {
    const float* x    = (const float*)d_in[0];
    const int*   ei   = (const int*)d_in[1];    // int32 (JAX x64 disabled)
    const float* W1   = (const float*)d_in[2];
    const float* b1   = (const float*)d_in[3];
    const float* W2   = (const float*)d_in[4];
    const float* b2   = (const float*)d_in[5];
    const float* Wout = (const float*)d_in[6];
    const float* bout = (const float*)d_in[7];
    float* out = (float*)d_out;

    // workspace layout — total ~72.3 MB
    char* ws = (char*)d_ws;
    size_t off = 0;
    float*    norm  = (float*)(ws + off);    off += (size_t)N_EDGE * 4;        // 10.24 MB
    unsigned* deg   = (unsigned*)(ws + off); off += (size_t)N_NODES * 4;       // 0.32 MB
    float*    dinv  = (float*)(ws + off);    off += (size_t)N_NODES * 4;       // 0.32 MB
    float*    xW1   = (float*)(ws + off);    off += (size_t)N_NODES * H1 * 4;  // 10.24 MB
    float*    agg1  = (float*)(ws + off);    off += (size_t)N_NODES * H1 * 4;  // 10.24 MB
    float*    h2    = (float*)(ws + off);    off += (size_t)N_NODES * H2 * 4;  // 20.48 MB
    float*    agg2  = (float*)(ws + off);    off += (size_t)N_NODES * H2 * 4;  // 20.48 MB
    double*   partial = (double*)(ws + off); off += NB * 8;
    (void)ws_size; (void)in_sizes; (void)n_in; (void)out_size;

    const int B = 256;
    k_init<<<(N_NODES + B - 1) / B, B, 0, stream>>>(deg, partial);
    k_deg<<<(N_EDGE + B - 1) / B, B, 0, stream>>>(ei, deg);
    k_dinv<<<(N_NODES + B - 1) / B, B, 0, stream>>>(deg, dinv);
    k_norm<<<(N_EDGE + B - 1) / B, B, 0, stream>>>(ei, dinv, norm);
    k_gemm1<<<N_NODES / 8, B, 0, stream>>>(x, W1, dinv, xW1, agg1);

    int s1_threads = N_EDGE * H1;              // 81,920,000
    k_scatter1<<<(s1_threads + B - 1) / B, B, 0, stream>>>(ei, norm, xW1, agg1);

    k_gemm2<<<N_NODES / 4, B, 0, stream>>>(agg1, b1, W2, dinv, h2, agg2);

    int s2_threads = N_EDGE * H2;              // 163,840,000 (< 2^31)
    k_scatter2<<<(s2_threads + B - 1) / B, B, 0, stream>>>(ei, norm, h2, agg2);

    dim3 fgrid(160, NB);
    k_final<<<fgrid, B, 0, stream>>>(agg2, b2, Wout, partial);
    k_out<<<1, 64, 0, stream>>>(partial, bout, out);
}